// Round 8
// baseline (419.051 us; speedup 1.0000x reference)
//
#include <hip/hip_runtime.h>
#include <hip/hip_cooperative_groups.h>
namespace cg = cooperative_groups;

#define NN 2048
#define WW 32            // u64 words per bitmask row
#define DD 512
#define MS 512           // super nodes
#define TGTM 1536        // merges = NN - MS
#define KSH 14           // key scale bits: 2^14 > union_max^2 (~9025) -> exact order
#define KMAX16 16384u    // max key value (jac == 1)
#define CB 64            // cooperative blocks
#define CT 1024          // cooperative threads/block
#define ASL 64           // coarseA members per slice
#define NSL 25           // 25*64=1600 >= max cluster size 1537

typedef unsigned long long ull;
typedef unsigned short u16;

__device__ __forceinline__ void atomicMin64(ull* p, ull v){
  ull old = *p;
  while (v < old){
    ull assumed = old;
    old = atomicCAS(p, assumed, v);
    if (old == assumed) break;
  }
}

// Build 2048-bit adjacency bitmasks + degrees (wave-reduced).
__global__ void k_build_bits(const float* __restrict__ A, ull* __restrict__ bits,
                             unsigned* __restrict__ deg){
  int gid = blockIdx.x*blockDim.x + threadIdx.x;   // NN*WW threads
  int i = gid >> 5, w = gid & 31;
  const float4* row = (const float4*)(A + ((size_t)i << 11) + (w << 6));
  ull m = 0ull;
  #pragma unroll
  for (int k = 0; k < 16; ++k){
    float4 v = row[k];
    if (v.x > 0.0f) m |= (1ull << (4*k+0));
    if (v.y > 0.0f) m |= (1ull << (4*k+1));
    if (v.z > 0.0f) m |= (1ull << (4*k+2));
    if (v.w > 0.0f) m |= (1ull << (4*k+3));
  }
  bits[((size_t)i << 5) + w] = m;
  unsigned p = (unsigned)__popcll(m);
  for (int off = 16; off; off >>= 1) p += __shfl_xor(p, off, 32);
  if (w == 0) deg[i] = p;
}

// Key matrix (u16): key = round(inter * 2^14 / union). Exact rational order
// for union_max^2 < 2^14 (deg_max ~45 here -> union <= ~95, 95^2 = 9025).
__global__ void k_keymat(const ull* __restrict__ bits,
                         const unsigned* __restrict__ deg, u16* __restrict__ keyM){
  __shared__ ull bi[64][33];
  __shared__ ull bj[64][33];
  __shared__ unsigned degi[64], degj[64];
  int ib = blockIdx.x, jb = blockIdx.y;
  int t = threadIdx.x;
  for (int idx = t; idx < 64*32; idx += 256){
    int r = idx >> 5, w = idx & 31;
    bi[r][w] = bits[(((size_t)(ib*64 + r)) << 5) + w];
    bj[r][w] = bits[(((size_t)(jb*64 + r)) << 5) + w];
  }
  if (t < 64){ degi[t] = deg[ib*64 + t]; degj[t] = deg[jb*64 + t]; }
  __syncthreads();
  for (int p = t; p < 4096; p += 256){
    int ii = p >> 6, jj = p & 63;
    int i = ib*64 + ii, j = jb*64 + jj;
    unsigned key = 0u;
    if (i != j){
      unsigned inter = 0;
      #pragma unroll
      for (int w = 0; w < 32; ++w) inter += (unsigned)__popcll(bi[ii][w] & bj[jj][w]);
      unsigned b = degi[ii] + degj[jj] - inter;
      if (b != 0u){
        unsigned num = (inter << KSH) + (b >> 1);   // fits u32 (inter<=~95)
        key = num / b;                              // u32 divide
      }
    }
    keyM[((size_t)i << 11) + j] = (u16)key;
  }
}

// Fused Boruvka + finalization, ONE grid.sync per round, redundant merge in
// every block (bit-identical LDS state). u16 keys, ushort4 row loads.
__global__ void __launch_bounds__(CT)
k_boruvka(const u16* __restrict__ keyM, ull* __restrict__ node_best /*[2][NN]*/,
          unsigned* __restrict__ labels_g, float* __restrict__ scale_g,
          unsigned* __restrict__ offs_g, unsigned* __restrict__ memb_g,
          float* __restrict__ P){
  cg::grid_group grid = cg::this_grid();
  __shared__ ull ed[NN];       // collected MSF edges; later sort buffer / fo / plab
  __shared__ ull cbest[NN];    // per-component best; later sizes/scanT
  __shared__ unsigned lab[NN]; // per-block comp copy; later CC labels
  __shared__ unsigned nxtA[NN], nxtB[NN];
  __shared__ int flagS;
  __shared__ unsigned cntS;
  int t = threadIdx.x;
  int b = blockIdx.x;
  if (t == 0) cntS = 0;
  for (int i = t; i < NN; i += CT) lab[i] = (unsigned)i;
  __syncthreads();

  for (int round = 0; round < 11; ++round){
    ull* nb = node_best + ((round & 1) ? NN : 0);
    // ---- best phase: this block's 32 rows, 2 per wave, 4 keys per load ----
    {
      int wv = b*(CT/64) + (t >> 6);     // global wave id 0..1023
      int lane = t & 63;
      #pragma unroll
      for (int rr = 0; rr < 2; ++rr){
        int i = wv*2 + rr;
        unsigned ci = lab[i];
        const u16* row = keyM + ((size_t)i << 11);
        ull best = ~0ull;
        #pragma unroll
        for (int it = 0; it < 8; ++it){
          int j0 = it*256 + lane*4;
          ushort4 k4 = *(const ushort4*)(row + j0);
          uint4   c4 = *(const uint4*)(lab + j0);    // 16B-aligned LDS read
          #pragma unroll
          for (int q = 0; q < 4; ++q){
            int j = j0 + q;
            unsigned key = (q==0)?k4.x:(q==1)?k4.y:(q==2)?k4.z:k4.w;
            unsigned cj  = (q==0)?c4.x:(q==1)?c4.y:(q==2)?c4.z:c4.w;
            if (j == i || cj == ci) continue;
            unsigned kp = KMAX16 - key;
            unsigned a  = (i < j) ? (unsigned)i : (unsigned)j;
            unsigned b2 = (i < j) ? (unsigned)j : (unsigned)i;
            ull v = (((ull)kp) << 22) | (((ull)a) << 11) | b2;
            if (v < best) best = v;
          }
        }
        for (int off = 32; off; off >>= 1){
          ull o = __shfl_xor(best, off);
          if (o < best) best = o;
        }
        if (lane == 0) nb[i] = best;
      }
    }
    grid.sync();
    // ---- merge phase: ALL blocks, redundant & identical ----
    for (int c = t; c < NN; c += CT) cbest[c] = ~0ull;
    __syncthreads();
    for (int i = t; i < NN; i += CT) atomicMin64(&cbest[lab[i]], nb[i]);
    __syncthreads();
    for (int c = t; c < NN; c += CT){
      unsigned nx = (unsigned)c;
      ull v = cbest[c];
      if (v != ~0ull){
        unsigned a = (unsigned)((v >> 11) & 2047u), b2 = (unsigned)(v & 2047u);
        unsigned la = lab[a], lb = lab[b2];
        if (la != lb) nx = (la == (unsigned)c) ? lb : la;
      }
      nxtA[c] = nx;
    }
    __syncthreads();
    for (int c = t; c < NN; c += CT){
      unsigned o = nxtA[c];
      if (o != (unsigned)c && nxtA[o] == (unsigned)c && (unsigned)c < o) nxtA[c] = (unsigned)c;
    }
    __syncthreads();
    for (int c = t; c < NN; c += CT){
      if (nxtA[c] != (unsigned)c){
        unsigned idx = atomicAdd(&cntS, 1u);
        if (idx < (unsigned)NN) ed[idx] = cbest[c];
      }
    }
    __syncthreads();
    unsigned* s1 = nxtA; unsigned* s2 = nxtB;
    for (int r = 0; r < 11; ++r){
      if (t == 0) flagS = 0;
      __syncthreads();
      int ch = 0;
      for (int c = t; c < NN; c += CT){ unsigned p = s1[c], g = s1[p]; s2[c] = g; ch |= (g != p); }
      if (ch) flagS = 1;
      __syncthreads();
      unsigned* tmp = s1; s1 = s2; s2 = tmp;
      int f = flagS;
      __syncthreads();
      if (!f) break;
    }
    for (int i = t; i < NN; i += CT) lab[i] = s1[lab[i]];
    __syncthreads();
    if (cntS >= (unsigned)(NN-1)) break;   // identical in every block
  }
  if (b != 0) return;

  // ================= final phase (block 0 only) =================
  unsigned cnt = cntS; if (cnt > (unsigned)NN) cnt = NN;
  for (int i = t; i < NN; i += CT) if (i >= (int)cnt) ed[i] = ~0ull;
  __syncthreads();
  // bitonic sort ascending (vals unique; pads sort last)
  for (unsigned k = 2; k <= (unsigned)NN; k <<= 1)
    for (unsigned j = k >> 1; j > 0; j >>= 1){
      for (int i = t; i < NN; i += CT){
        unsigned l = ((unsigned)i) ^ j;
        if (l > (unsigned)i){
          bool up = ((((unsigned)i) & k) == 0u);
          ull x = ed[i], y = ed[l];
          if ((x > y) == up){ ed[i] = y; ed[l] = x; }
        }
      }
      __syncthreads();
    }
  // CC of first TGTM edges, hooking rounds with convergence early-exit
  for (int i = t; i < NN; i += CT) lab[i] = (unsigned)i;
  __syncthreads();
  for (int round = 0; round < 11; ++round){
    if (t == 0) flagS = 0;
    for (int c = t; c < NN; c += CT) cbest[c] = ~0ull;
    __syncthreads();
    for (int e = t; e < TGTM; e += CT){
      ull v = ed[e];
      unsigned a = (unsigned)((v >> 11) & 2047u), b2 = (unsigned)(v & 2047u);
      unsigned la = lab[a], lb = lab[b2];
      if (la != lb){ atomicMin64(&cbest[la], v); atomicMin64(&cbest[lb], v); flagS = 1; }
    }
    __syncthreads();
    int active = flagS;
    __syncthreads();
    if (!active) break;
    for (int c = t; c < NN; c += CT){
      unsigned nx = (unsigned)c;
      ull v = cbest[c];
      if (v != ~0ull){
        unsigned a = (unsigned)((v >> 11) & 2047u), b2 = (unsigned)(v & 2047u);
        unsigned la = lab[a], lb = lab[b2];
        if (la != lb) nx = (la == (unsigned)c) ? lb : la;
      }
      nxtA[c] = nx;
    }
    __syncthreads();
    for (int c = t; c < NN; c += CT){
      unsigned o = nxtA[c];
      if (o != (unsigned)c && nxtA[o] == (unsigned)c && (unsigned)c < o) nxtA[c] = (unsigned)c;
    }
    __syncthreads();
    unsigned* s1 = nxtA; unsigned* s2 = nxtB;
    for (int r = 0; r < 11; ++r){
      if (t == 0) flagS = 0;
      __syncthreads();
      int ch = 0;
      for (int c = t; c < NN; c += CT){ unsigned p = s1[c], g = s1[p]; s2[c] = g; ch |= (g != p); }
      if (ch) flagS = 1;
      __syncthreads();
      unsigned* tmp = s1; s1 = s2; s2 = tmp;
      int f = flagS;
      __syncthreads();
      if (!f) break;
    }
    for (int i = t; i < NN; i += CT) lab[i] = s1[lab[i]];
    __syncthreads();
  }
  // labels = rank of class by min member; sizes; scale; member lists; P
  unsigned* fo    = (unsigned*)ed;
  unsigned* plab  = ((unsigned*)ed) + NN;
  unsigned* sizes = (unsigned*)cbest;          // [0,512)
  unsigned* scanT = ((unsigned*)cbest) + 1024; // 1024 entries
  for (int i = t; i < NN; i += CT) fo[i] = 0xFFFFFFFFu;
  __syncthreads();
  for (int i = t; i < NN; i += CT) atomicMin(&fo[lab[i]], (unsigned)i);
  __syncthreads();
  int i0 = 2*t, i1 = 2*t + 1;
  unsigned f0 = (fo[lab[i0]] == (unsigned)i0) ? 1u : 0u;
  unsigned f1 = (fo[lab[i1]] == (unsigned)i1) ? 1u : 0u;
  unsigned s = f0 + f1;
  scanT[t] = s; __syncthreads();
  for (int off = 1; off < CT; off <<= 1){
    unsigned x = (t >= off) ? scanT[t-off] : 0u;
    __syncthreads();
    scanT[t] += x;
    __syncthreads();
  }
  unsigned excl = scanT[t] - s;
  plab[i0] = excl; plab[i1] = excl + f0;
  __syncthreads();
  for (int c = t; c < MS; c += CT) sizes[c] = 0u;
  __syncthreads();
  for (int i = t; i < NN; i += CT){
    unsigned L = plab[fo[lab[i]]];
    labels_g[i] = L;
    if (L < (unsigned)MS) atomicAdd(&sizes[L], 1u);
  }
  __syncthreads();
  for (int c = t; c < MS; c += CT) scale_g[c] = 1.0f / sqrtf((float)sizes[c] + 1e-10f);
  // offs: exclusive scan of sizes
  unsigned* off_l  = nxtA;
  unsigned* cursor = nxtA + 1024;
  unsigned my = (t < MS) ? sizes[t] : 0u;
  scanT[t] = my; __syncthreads();
  for (int off = 1; off < CT; off <<= 1){
    unsigned x = (t >= off) ? scanT[t-off] : 0u;
    __syncthreads();
    scanT[t] += x;
    __syncthreads();
  }
  if (t < MS){
    unsigned ex = scanT[t] - my;
    off_l[t] = ex; offs_g[t] = ex;
  }
  if (t == 0) offs_g[MS] = (unsigned)NN;
  __syncthreads();
  for (int c = t; c < MS; c += CT) cursor[c] = off_l[c];
  __syncthreads();
  for (int i = t; i < NN; i += CT){
    unsigned L = plab[fo[lab[i]]];
    unsigned pos = atomicAdd(&cursor[L], 1u);
    memb_g[pos] = (unsigned)i;
  }
  for (int i = t; i < NN; i += CT){
    unsigned L = plab[fo[lab[i]]];
    P[((size_t)i << 9) + L] = 1.0f / sqrtf((float)sizes[L] + 1e-10f);
  }
}

// X_coarse: grid (cluster, d-tile of 128), 128 threads; LDS member list, 8-deep ILP.
__global__ void k_coarseX(const float* __restrict__ X, const unsigned* __restrict__ offs,
                          const unsigned* __restrict__ memb, const float* __restrict__ scale,
                          float* __restrict__ Xc){
  __shared__ unsigned mlist[NN];
  int c = blockIdx.x;
  int d = blockIdx.y*128 + threadIdx.x;
  unsigned o = offs[c], e = offs[c+1];
  int nm = (int)(e - o);
  for (int k = threadIdx.x; k < nm; k += 128) mlist[k] = memb[o + k];
  __syncthreads();
  float a0=0.f,a1=0.f,a2=0.f,a3=0.f,a4=0.f,a5=0.f,a6=0.f,a7=0.f;
  int k = 0;
  for (; k + 8 <= nm; k += 8){
    a0 += X[((size_t)mlist[k+0] << 9) + d];
    a1 += X[((size_t)mlist[k+1] << 9) + d];
    a2 += X[((size_t)mlist[k+2] << 9) + d];
    a3 += X[((size_t)mlist[k+3] << 9) + d];
    a4 += X[((size_t)mlist[k+4] << 9) + d];
    a5 += X[((size_t)mlist[k+5] << 9) + d];
    a6 += X[((size_t)mlist[k+6] << 9) + d];
    a7 += X[((size_t)mlist[k+7] << 9) + d];
  }
  for (; k < nm; ++k) a0 += X[((size_t)mlist[k] << 9) + d];
  float acc = ((a0+a1)+(a2+a3)) + ((a4+a5)+(a6+a7));
  Xc[((size_t)c << 9) + d] = acc * scale[c];
}

// A_coarse: grid (cluster, slice of <=64 members), LDS histogram per slice.
__global__ void k_coarseA(const ull* __restrict__ bits,
                          const unsigned* __restrict__ labels,
                          const unsigned* __restrict__ offs, const unsigned* __restrict__ memb,
                          const float* __restrict__ scale, float* __restrict__ Ac){
  __shared__ float row[MS];
  __shared__ unsigned labS[NN];
  __shared__ unsigned mlist[ASL];
  int c = blockIdx.x, sl = blockIdx.y, t = threadIdx.x;
  unsigned o0 = offs[c], e = offs[c+1];
  unsigned o = o0 + (unsigned)sl*ASL;
  if (o >= e) return;                       // uniform per block
  int nm = (int)min((unsigned)ASL, e - o);
  for (int j = t; j < MS; j += 256) row[j] = 0.0f;
  for (int i = t; i < NN; i += 256) labS[i] = labels[i];
  if (t < nm) mlist[t] = memb[o + t];
  __syncthreads();
  for (int idx = t; idx < nm*WW; idx += 256){
    unsigned m = mlist[idx >> 5];
    int w = idx & 31;
    ull word = bits[((size_t)m << 5) + w];
    while (word){
      int bb = __ffsll((long long)word) - 1;
      unsigned j = (unsigned)(w*64 + bb);
      atomicAdd(&row[labS[j]], 1.0f);       // LDS atomic
      word &= word - 1ull;
    }
  }
  __syncthreads();
  float sc = scale[c];
  bool single = (e - o0) <= (unsigned)ASL;
  if (single){
    for (int j = t; j < MS; j += 256)
      Ac[((size_t)c << 9) + j] = row[j] * sc * scale[j];
  } else {
    for (int j = t; j < MS; j += 256){
      float v = row[j];
      if (v != 0.0f) atomicAdd(&Ac[((size_t)c << 9) + j], v * sc * scale[j]);
    }
  }
}

extern "C" void kernel_launch(void* const* d_in, const int* in_sizes, int n_in,
                              void* d_out, int out_size, void* d_ws, size_t ws_size,
                              hipStream_t stream) {
  const float* X = (const float*)d_in[0];
  const float* A = (const float*)d_in[1];
  float* out = (float*)d_out;
  char* ws = (char*)d_ws;
  ull*      bits     = (ull*)     (ws + 0x000000);  // 512 KB, live whole run
  unsigned* deg      = (unsigned*)(ws + 0x080000);  // 8 KB (dead after keymat)
  ull*      nodebest = (ull*)     (ws + 0x084000);  // 32 KB double-buffered (dead after boruvka)
  unsigned* labels   = (unsigned*)(ws + 0x08D000);  // 8 KB
  float*    scale    = (float*)   (ws + 0x08F000);  // 2 KB
  unsigned* memb     = (unsigned*)(ws + 0x084000);  // overlays nodebest (8 KB)
  unsigned* offs     = (unsigned*)(ws + 0x080000);  // overlays deg (2052 B)
  u16*      keyM     = (u16*)     (ws + 0x090000);  // 8 MB

  float* Xc = out;
  float* Ac = out + MS*MS;
  float* P  = out + 2*MS*MS;

  hipMemsetAsync(P,  0, (size_t)NN*MS*sizeof(float), stream);   // P region (4 MB)
  hipMemsetAsync(Ac, 0, (size_t)MS*MS*sizeof(float), stream);   // Ac region (1 MB)

  k_build_bits<<<(NN*WW)/256, 256, 0, stream>>>(A, bits, deg);
  k_keymat<<<dim3(NN/64, NN/64), 256, 0, stream>>>(bits, deg, keyM);

  void* args[] = { (void*)&keyM, (void*)&nodebest,
                   (void*)&labels, (void*)&scale, (void*)&offs, (void*)&memb, (void*)&P };
  hipLaunchCooperativeKernel((void*)k_boruvka, dim3(CB), dim3(CT), args, 0, stream);

  k_coarseX<<<dim3(MS, DD/128), 128, 0, stream>>>(X, offs, memb, scale, Xc);
  k_coarseA<<<dim3(MS, NSL), 256, 0, stream>>>(bits, labels, offs, memb, scale, Ac);
}

// Round 9
// 363.247 us; speedup vs baseline: 1.1536x; 1.1536x over previous
//
#include <hip/hip_runtime.h>

#define NN 2048
#define WW 32            // u64 words per bitmask row
#define DD 512
#define MS 512           // super nodes
#define TGTM 1536        // merges = NN - MS
#define KSH 14           // key scale bits: 2^14 > union_max^2 -> exact rational order
#define KMAX16 16384u
#define CB 128           // cooperative blocks (1 row per wave: 128*16 = 2048)
#define CT 1024
#define ASL 64           // coarseA members per slice
#define NSL 25

typedef unsigned long long ull;
typedef unsigned short u16;

__device__ __forceinline__ void atomicMin64(ull* p, ull v){
  ull old = *p;
  while (v < old){
    ull assumed = old;
    old = atomicCAS(p, assumed, v);
    if (old == assumed) break;
  }
}

// Hand-rolled grid barrier: single monotone counter, no reset (target = k*CB).
// Arrive: device-scope RMW. Poll: device-scope LOAD (no RMW serialization).
__device__ __forceinline__ void gbar(unsigned* cnt, unsigned target, int t){
  __syncthreads();
  if (t == 0){
    __threadfence();                                   // release prior writes
    __hip_atomic_fetch_add(cnt, 1u, __ATOMIC_RELEASE, __HIP_MEMORY_SCOPE_AGENT);
    while (__hip_atomic_load(cnt, __ATOMIC_RELAXED, __HIP_MEMORY_SCOPE_AGENT) < target)
      __builtin_amdgcn_s_sleep(1);
    __threadfence();                                   // acquire others' writes
  }
  __syncthreads();
}

// Build 2048-bit adjacency bitmasks + degrees (wave-reduced).
__global__ void k_build_bits(const float* __restrict__ A, ull* __restrict__ bits,
                             unsigned* __restrict__ deg){
  int gid = blockIdx.x*blockDim.x + threadIdx.x;   // NN*WW threads
  int i = gid >> 5, w = gid & 31;
  const float4* row = (const float4*)(A + ((size_t)i << 11) + (w << 6));
  ull m = 0ull;
  #pragma unroll
  for (int k = 0; k < 16; ++k){
    float4 v = row[k];
    if (v.x > 0.0f) m |= (1ull << (4*k+0));
    if (v.y > 0.0f) m |= (1ull << (4*k+1));
    if (v.z > 0.0f) m |= (1ull << (4*k+2));
    if (v.w > 0.0f) m |= (1ull << (4*k+3));
  }
  bits[((size_t)i << 5) + w] = m;
  unsigned p = (unsigned)__popcll(m);
  for (int off = 16; off; off >>= 1) p += __shfl_xor(p, off, 32);
  if (w == 0) deg[i] = p;
}

// Key matrix (u16): key = round(inter * 2^14 / union). Exact rational order.
__global__ void k_keymat(const ull* __restrict__ bits,
                         const unsigned* __restrict__ deg, u16* __restrict__ keyM){
  __shared__ ull bi[64][33];
  __shared__ ull bj[64][33];
  __shared__ unsigned degi[64], degj[64];
  int ib = blockIdx.x, jb = blockIdx.y;
  int t = threadIdx.x;
  for (int idx = t; idx < 64*32; idx += 256){
    int r = idx >> 5, w = idx & 31;
    bi[r][w] = bits[(((size_t)(ib*64 + r)) << 5) + w];
    bj[r][w] = bits[(((size_t)(jb*64 + r)) << 5) + w];
  }
  if (t < 64){ degi[t] = deg[ib*64 + t]; degj[t] = deg[jb*64 + t]; }
  __syncthreads();
  for (int p = t; p < 4096; p += 256){
    int ii = p >> 6, jj = p & 63;
    int i = ib*64 + ii, j = jb*64 + jj;
    unsigned key = 0u;
    if (i != j){
      unsigned inter = 0;
      #pragma unroll
      for (int w = 0; w < 32; ++w) inter += (unsigned)__popcll(bi[ii][w] & bj[jj][w]);
      unsigned b = degi[ii] + degj[jj] - inter;
      if (b != 0u){
        unsigned num = (inter << KSH) + (b >> 1);
        key = num / b;
      }
    }
    keyM[((size_t)i << 11) + j] = (u16)key;
  }
}

// Fused Boruvka + finalization. One custom grid barrier per round; redundant
// merge in every block (bit-identical LDS state); barrier-diet merge.
__global__ void __launch_bounds__(CT)
k_boruvka(const u16* __restrict__ keyM, ull* __restrict__ node_best /*[2][NN]*/,
          unsigned* __restrict__ bar,
          unsigned* __restrict__ labels_g, float* __restrict__ scale_g,
          unsigned* __restrict__ offs_g, unsigned* __restrict__ memb_g,
          float* __restrict__ P){
  __shared__ ull ed[NN];       // collected MSF edges; later sort buffer / fo / plab
  __shared__ ull cbest[NN];    // per-component best; later sizes/scanT
  __shared__ alignas(16) unsigned lab[NN]; // comp copy; later CC labels
  __shared__ unsigned nxtA[NN], nxtB[NN];
  __shared__ unsigned flg[2];
  __shared__ int flagS;
  __shared__ unsigned cntS;
  int t = threadIdx.x;
  int b = blockIdx.x;
  if (t == 0) cntS = 0;
  for (int i = t; i < NN; i += CT) lab[i] = (unsigned)i;
  __syncthreads();

  for (int round = 0; round < 11; ++round){
    ull* nb = node_best + ((round & 1) ? NN : 0);
    // ---- best phase: one row per wave ----
    {
      int i = b*(CT/64) + (t >> 6);
      int lane = t & 63;
      unsigned ci = lab[i];
      const u16* row = keyM + ((size_t)i << 11);
      ull best = ~0ull;
      #pragma unroll
      for (int it = 0; it < 8; ++it){
        int j0 = it*256 + lane*4;
        ushort4 k4 = *(const ushort4*)(row + j0);
        uint4   c4 = *(const uint4*)(lab + j0);
        #pragma unroll
        for (int q = 0; q < 4; ++q){
          int j = j0 + q;
          unsigned key = (q==0)?k4.x:(q==1)?k4.y:(q==2)?k4.z:k4.w;
          unsigned cj  = (q==0)?c4.x:(q==1)?c4.y:(q==2)?c4.z:c4.w;
          if (j == i || cj == ci) continue;
          unsigned kp = KMAX16 - key;
          unsigned a  = (i < j) ? (unsigned)i : (unsigned)j;
          unsigned b2 = (i < j) ? (unsigned)j : (unsigned)i;
          ull v = (((ull)kp) << 22) | (((ull)a) << 11) | b2;
          if (v < best) best = v;
        }
      }
      for (int off = 32; off; off >>= 1){
        ull o = __shfl_xor(best, off);
        if (o < best) best = o;
      }
      if (lane == 0) nb[i] = best;
    }
    gbar(bar, (unsigned)(round + 1) * (unsigned)CB, t);
    // ---- merge phase: ALL blocks, redundant & identical, barrier-diet ----
    for (int c = t; c < NN; c += CT) cbest[c] = ~0ull;
    if (t < 2) flg[t] = 0u;
    __syncthreads();                                           // B1
    for (int i = t; i < NN; i += CT) atomicMin64(&cbest[lab[i]], nb[i]);
    __syncthreads();                                           // B2
    for (int c = t; c < NN; c += CT){
      unsigned nx = (unsigned)c;
      ull v = cbest[c];
      if (v != ~0ull){
        unsigned a = (unsigned)((v >> 11) & 2047u), b2 = (unsigned)(v & 2047u);
        unsigned la = lab[a], lb = lab[b2];
        if (la != lb) nx = (la == (unsigned)c) ? lb : la;
      }
      nxtA[c] = nx;
    }
    __syncthreads();                                           // B3
    for (int c = t; c < NN; c += CT){
      unsigned o = nxtA[c];
      if (o != (unsigned)c && nxtA[o] == (unsigned)c && (unsigned)c < o) nxtA[c] = (unsigned)c;
    }
    __syncthreads();                                           // B4
    unsigned* s1 = nxtA; unsigned* s2 = nxtB;
    // doubling iter 0 fused with edge collect
    for (int c = t; c < NN; c += CT){
      unsigned p = s1[c];
      s2[c] = s1[p];
      if (p != (unsigned)c){
        unsigned idx = atomicAdd(&cntS, 1u);
        if (idx < (unsigned)NN) ed[idx] = cbest[c];
      }
    }
    __syncthreads();                                           // B5
    { unsigned* tmp = s1; s1 = s2; s2 = tmp; }
    // fixed doubling iters 1,2
    #pragma unroll
    for (int r = 1; r <= 2; ++r){
      for (int c = t; c < NN; c += CT) s2[c] = s1[s1[c]];
      __syncthreads();                                         // B6,B7
      unsigned* tmp = s1; s1 = s2; s2 = tmp;
    }
    // checked doubling iters (1 barrier each, parity flags)
    for (int r = 3; r < 11; ++r){
      int ch = 0;
      for (int c = t; c < NN; c += CT){ unsigned p = s1[c], g = s1[p]; s2[c] = g; ch |= (g != p); }
      if (ch) flg[r & 1] = 1u;
      if (t == 0) flg[(r + 1) & 1] = 0u;
      __syncthreads();                                         // B8..
      unsigned* tmp = s1; s1 = s2; s2 = tmp;
      if (!flg[r & 1]) break;
    }
    for (int i = t; i < NN; i += CT) lab[i] = s1[lab[i]];
    __syncthreads();                                           // B9
    if (cntS >= (unsigned)(NN-1)) break;   // identical in every block
  }
  if (b != 0) return;

  // ================= final phase (block 0 only) =================
  unsigned cnt = cntS; if (cnt > (unsigned)NN) cnt = NN;
  for (int i = t; i < NN; i += CT) if (i >= (int)cnt) ed[i] = ~0ull;
  __syncthreads();
  // bitonic sort ascending (vals unique; pads sort last)
  for (unsigned k = 2; k <= (unsigned)NN; k <<= 1)
    for (unsigned j = k >> 1; j > 0; j >>= 1){
      for (int i = t; i < NN; i += CT){
        unsigned l = ((unsigned)i) ^ j;
        if (l > (unsigned)i){
          bool up = ((((unsigned)i) & k) == 0u);
          ull x = ed[i], y = ed[l];
          if ((x > y) == up){ ed[i] = y; ed[l] = x; }
        }
      }
      __syncthreads();
    }
  // CC of first TGTM edges, hooking rounds with convergence early-exit
  for (int i = t; i < NN; i += CT) lab[i] = (unsigned)i;
  __syncthreads();
  for (int round = 0; round < 11; ++round){
    if (t == 0) flagS = 0;
    for (int c = t; c < NN; c += CT) cbest[c] = ~0ull;
    __syncthreads();
    for (int e = t; e < TGTM; e += CT){
      ull v = ed[e];
      unsigned a = (unsigned)((v >> 11) & 2047u), b2 = (unsigned)(v & 2047u);
      unsigned la = lab[a], lb = lab[b2];
      if (la != lb){ atomicMin64(&cbest[la], v); atomicMin64(&cbest[lb], v); flagS = 1; }
    }
    __syncthreads();
    int active = flagS;
    __syncthreads();
    if (!active) break;
    for (int c = t; c < NN; c += CT){
      unsigned nx = (unsigned)c;
      ull v = cbest[c];
      if (v != ~0ull){
        unsigned a = (unsigned)((v >> 11) & 2047u), b2 = (unsigned)(v & 2047u);
        unsigned la = lab[a], lb = lab[b2];
        if (la != lb) nx = (la == (unsigned)c) ? lb : la;
      }
      nxtA[c] = nx;
    }
    __syncthreads();
    for (int c = t; c < NN; c += CT){
      unsigned o = nxtA[c];
      if (o != (unsigned)c && nxtA[o] == (unsigned)c && (unsigned)c < o) nxtA[c] = (unsigned)c;
    }
    __syncthreads();
    unsigned* s1 = nxtA; unsigned* s2 = nxtB;
    for (int r = 0; r < 11; ++r){
      if (t == 0) flagS = 0;
      __syncthreads();
      int ch = 0;
      for (int c = t; c < NN; c += CT){ unsigned p = s1[c], g = s1[p]; s2[c] = g; ch |= (g != p); }
      if (ch) flagS = 1;
      __syncthreads();
      unsigned* tmp = s1; s1 = s2; s2 = tmp;
      int f = flagS;
      __syncthreads();
      if (!f) break;
    }
    for (int i = t; i < NN; i += CT) lab[i] = s1[lab[i]];
    __syncthreads();
  }
  // labels = rank of class by min member; sizes; scale; member lists; P
  unsigned* fo    = (unsigned*)ed;
  unsigned* plab  = ((unsigned*)ed) + NN;
  unsigned* sizes = (unsigned*)cbest;          // [0,512)
  unsigned* scanT = ((unsigned*)cbest) + 1024; // 1024 entries
  for (int i = t; i < NN; i += CT) fo[i] = 0xFFFFFFFFu;
  __syncthreads();
  for (int i = t; i < NN; i += CT) atomicMin(&fo[lab[i]], (unsigned)i);
  __syncthreads();
  int i0 = 2*t, i1 = 2*t + 1;
  unsigned f0 = (fo[lab[i0]] == (unsigned)i0) ? 1u : 0u;
  unsigned f1 = (fo[lab[i1]] == (unsigned)i1) ? 1u : 0u;
  unsigned s = f0 + f1;
  scanT[t] = s; __syncthreads();
  for (int off = 1; off < CT; off <<= 1){
    unsigned x = (t >= off) ? scanT[t-off] : 0u;
    __syncthreads();
    scanT[t] += x;
    __syncthreads();
  }
  unsigned excl = scanT[t] - s;
  plab[i0] = excl; plab[i1] = excl + f0;
  __syncthreads();
  for (int c = t; c < MS; c += CT) sizes[c] = 0u;
  __syncthreads();
  for (int i = t; i < NN; i += CT){
    unsigned L = plab[fo[lab[i]]];
    labels_g[i] = L;
    if (L < (unsigned)MS) atomicAdd(&sizes[L], 1u);
  }
  __syncthreads();
  for (int c = t; c < MS; c += CT) scale_g[c] = 1.0f / sqrtf((float)sizes[c] + 1e-10f);
  // offs: exclusive scan of sizes
  unsigned* off_l  = nxtA;
  unsigned* cursor = nxtA + 1024;
  unsigned my = (t < MS) ? sizes[t] : 0u;
  scanT[t] = my; __syncthreads();
  for (int off = 1; off < CT; off <<= 1){
    unsigned x = (t >= off) ? scanT[t-off] : 0u;
    __syncthreads();
    scanT[t] += x;
    __syncthreads();
  }
  if (t < MS){
    unsigned ex = scanT[t] - my;
    off_l[t] = ex; offs_g[t] = ex;
  }
  if (t == 0) offs_g[MS] = (unsigned)NN;
  __syncthreads();
  for (int c = t; c < MS; c += CT) cursor[c] = off_l[c];
  __syncthreads();
  for (int i = t; i < NN; i += CT){
    unsigned L = plab[fo[lab[i]]];
    unsigned pos = atomicAdd(&cursor[L], 1u);
    memb_g[pos] = (unsigned)i;
  }
  for (int i = t; i < NN; i += CT){
    unsigned L = plab[fo[lab[i]]];
    P[((size_t)i << 9) + L] = 1.0f / sqrtf((float)sizes[L] + 1e-10f);
  }
}

// X_coarse: grid (cluster, d-tile of 128), 128 threads; LDS member list, 8-deep ILP.
__global__ void k_coarseX(const float* __restrict__ X, const unsigned* __restrict__ offs,
                          const unsigned* __restrict__ memb, const float* __restrict__ scale,
                          float* __restrict__ Xc){
  __shared__ unsigned mlist[NN];
  int c = blockIdx.x;
  int d = blockIdx.y*128 + threadIdx.x;
  unsigned o = offs[c], e = offs[c+1];
  int nm = (int)(e - o);
  for (int k = threadIdx.x; k < nm; k += 128) mlist[k] = memb[o + k];
  __syncthreads();
  float a0=0.f,a1=0.f,a2=0.f,a3=0.f,a4=0.f,a5=0.f,a6=0.f,a7=0.f;
  int k = 0;
  for (; k + 8 <= nm; k += 8){
    a0 += X[((size_t)mlist[k+0] << 9) + d];
    a1 += X[((size_t)mlist[k+1] << 9) + d];
    a2 += X[((size_t)mlist[k+2] << 9) + d];
    a3 += X[((size_t)mlist[k+3] << 9) + d];
    a4 += X[((size_t)mlist[k+4] << 9) + d];
    a5 += X[((size_t)mlist[k+5] << 9) + d];
    a6 += X[((size_t)mlist[k+6] << 9) + d];
    a7 += X[((size_t)mlist[k+7] << 9) + d];
  }
  for (; k < nm; ++k) a0 += X[((size_t)mlist[k] << 9) + d];
  float acc = ((a0+a1)+(a2+a3)) + ((a4+a5)+(a6+a7));
  Xc[((size_t)c << 9) + d] = acc * scale[c];
}

// A_coarse: grid (cluster, slice of <=64 members), LDS histogram per slice.
__global__ void k_coarseA(const ull* __restrict__ bits,
                          const unsigned* __restrict__ labels,
                          const unsigned* __restrict__ offs, const unsigned* __restrict__ memb,
                          const float* __restrict__ scale, float* __restrict__ Ac){
  __shared__ float row[MS];
  __shared__ unsigned labS[NN];
  __shared__ unsigned mlist[ASL];
  int c = blockIdx.x, sl = blockIdx.y, t = threadIdx.x;
  unsigned o0 = offs[c], e = offs[c+1];
  unsigned o = o0 + (unsigned)sl*ASL;
  if (o >= e) return;                       // uniform per block
  int nm = (int)min((unsigned)ASL, e - o);
  for (int j = t; j < MS; j += 256) row[j] = 0.0f;
  for (int i = t; i < NN; i += 256) labS[i] = labels[i];
  if (t < nm) mlist[t] = memb[o + t];
  __syncthreads();
  for (int idx = t; idx < nm*WW; idx += 256){
    unsigned m = mlist[idx >> 5];
    int w = idx & 31;
    ull word = bits[((size_t)m << 5) + w];
    while (word){
      int bb = __ffsll((long long)word) - 1;
      unsigned j = (unsigned)(w*64 + bb);
      atomicAdd(&row[labS[j]], 1.0f);       // LDS atomic
      word &= word - 1ull;
    }
  }
  __syncthreads();
  float sc = scale[c];
  bool single = (e - o0) <= (unsigned)ASL;
  if (single){
    for (int j = t; j < MS; j += 256)
      Ac[((size_t)c << 9) + j] = row[j] * sc * scale[j];
  } else {
    for (int j = t; j < MS; j += 256){
      float v = row[j];
      if (v != 0.0f) atomicAdd(&Ac[((size_t)c << 9) + j], v * sc * scale[j]);
    }
  }
}

extern "C" void kernel_launch(void* const* d_in, const int* in_sizes, int n_in,
                              void* d_out, int out_size, void* d_ws, size_t ws_size,
                              hipStream_t stream) {
  const float* X = (const float*)d_in[0];
  const float* A = (const float*)d_in[1];
  float* out = (float*)d_out;
  char* ws = (char*)d_ws;
  ull*      bits     = (ull*)     (ws + 0x000000);  // 512 KB, live whole run
  unsigned* deg      = (unsigned*)(ws + 0x080000);  // 8 KB (dead after keymat)
  ull*      nodebest = (ull*)     (ws + 0x084000);  // 32 KB double-buffered
  unsigned* labels   = (unsigned*)(ws + 0x08D000);  // 8 KB
  float*    scale    = (float*)   (ws + 0x08F000);  // 2 KB
  unsigned* bar      = (unsigned*)(ws + 0x08F800);  // 8 B grid-barrier counter
  unsigned* memb     = (unsigned*)(ws + 0x084000);  // overlays nodebest (8 KB)
  unsigned* offs     = (unsigned*)(ws + 0x080000);  // overlays deg (2052 B)
  u16*      keyM     = (u16*)     (ws + 0x090000);  // 8 MB

  float* Xc = out;
  float* Ac = out + MS*MS;
  float* P  = out + 2*MS*MS;

  hipMemsetAsync(bar, 0, 8, stream);
  hipMemsetAsync(P,  0, (size_t)NN*MS*sizeof(float), stream);   // P region (4 MB)
  hipMemsetAsync(Ac, 0, (size_t)MS*MS*sizeof(float), stream);   // Ac region (1 MB)

  k_build_bits<<<(NN*WW)/256, 256, 0, stream>>>(A, bits, deg);
  k_keymat<<<dim3(NN/64, NN/64), 256, 0, stream>>>(bits, deg, keyM);

  void* args[] = { (void*)&keyM, (void*)&nodebest, (void*)&bar,
                   (void*)&labels, (void*)&scale, (void*)&offs, (void*)&memb, (void*)&P };
  hipLaunchCooperativeKernel((void*)k_boruvka, dim3(CB), dim3(CT), args, 0, stream);

  k_coarseX<<<dim3(MS, DD/128), 128, 0, stream>>>(X, offs, memb, scale, Xc);
  k_coarseA<<<dim3(MS, NSL), 256, 0, stream>>>(bits, labels, offs, memb, scale, Ac);
}

// Round 10
// 338.345 us; speedup vs baseline: 1.2385x; 1.0736x over previous
//
#include <hip/hip_runtime.h>

#define NN 2048
#define WW 32            // u64 words per bitmask row
#define DD 512
#define MS 512           // super nodes
#define TGTM 1536        // merges = NN - MS
#define KSH 14           // key scale bits: 2^14 > union_max^2 -> exact rational order
#define KMAX16 16384u
#define CB 128           // cooperative blocks (1 row per wave: 128*16 = 2048)
#define CT 1024
#define ASL 64           // coarseA members per slice
#define NSL 25

typedef unsigned long long ull;
typedef unsigned short u16;

__device__ __forceinline__ void atomicMin64(ull* p, ull v){
  ull old = *p;
  while (v < old){
    ull assumed = old;
    old = atomicCAS(p, assumed, v);
    if (old == assumed) break;
  }
}

// Lock-free union-find on LDS: hook larger root under smaller (root = min id),
// path halving on find (benign race: writes are always valid ancestors).
__device__ __forceinline__ unsigned uf_find(unsigned* par, unsigned x){
  while (true){
    unsigned p = par[x];
    if (p == x) return x;
    unsigned g = par[p];
    if (g == p) return p;
    par[x] = g;
    x = g;
  }
}
__device__ __forceinline__ void uf_union(unsigned* par, unsigned x, unsigned y){
  while (true){
    unsigned rx = uf_find(par, x), ry = uf_find(par, y);
    if (rx == ry) return;
    if (rx > ry){ unsigned tm = rx; rx = ry; ry = tm; }
    if (atomicCAS(&par[ry], ry, rx) == ry) return;
    x = rx; y = ry;
  }
}

// Inclusive block scan over CT=1024 threads: shfl wave scan + 16 partials.
__device__ __forceinline__ unsigned block_scan_incl(unsigned v, unsigned* partials, int t){
  int lane = t & 63, wv = t >> 6;
  unsigned x = v;
  #pragma unroll
  for (int off = 1; off < 64; off <<= 1){
    unsigned n = __shfl_up(x, off, 64);
    if (lane >= off) x += n;
  }
  __syncthreads();                 // protect partials reuse across calls
  if (lane == 63) partials[wv] = x;
  __syncthreads();
  if (wv == 0){
    unsigned p = (lane < 16) ? partials[lane] : 0u;
    #pragma unroll
    for (int off = 1; off < 16; off <<= 1){
      unsigned n = __shfl_up(p, off, 64);
      if (lane >= off) p += n;
    }
    if (lane < 16) partials[lane] = p;
  }
  __syncthreads();
  if (wv > 0) x += partials[wv-1];
  return x;
}

// Hand-rolled grid barrier: single monotone counter, no reset (target = k*CB).
__device__ __forceinline__ void gbar(unsigned* cnt, unsigned target, int t){
  __syncthreads();
  if (t == 0){
    __threadfence();
    __hip_atomic_fetch_add(cnt, 1u, __ATOMIC_RELEASE, __HIP_MEMORY_SCOPE_AGENT);
    while (__hip_atomic_load(cnt, __ATOMIC_RELAXED, __HIP_MEMORY_SCOPE_AGENT) < target)
      __builtin_amdgcn_s_sleep(1);
    __threadfence();
  }
  __syncthreads();
}

// Build 2048-bit adjacency bitmasks + degrees (wave-reduced).
__global__ void k_build_bits(const float* __restrict__ A, ull* __restrict__ bits,
                             unsigned* __restrict__ deg){
  int gid = blockIdx.x*blockDim.x + threadIdx.x;   // NN*WW threads
  int i = gid >> 5, w = gid & 31;
  const float4* row = (const float4*)(A + ((size_t)i << 11) + (w << 6));
  ull m = 0ull;
  #pragma unroll
  for (int k = 0; k < 16; ++k){
    float4 v = row[k];
    if (v.x > 0.0f) m |= (1ull << (4*k+0));
    if (v.y > 0.0f) m |= (1ull << (4*k+1));
    if (v.z > 0.0f) m |= (1ull << (4*k+2));
    if (v.w > 0.0f) m |= (1ull << (4*k+3));
  }
  bits[((size_t)i << 5) + w] = m;
  unsigned p = (unsigned)__popcll(m);
  for (int off = 16; off; off >>= 1) p += __shfl_xor(p, off, 32);
  if (w == 0) deg[i] = p;
}

// Key matrix (u16): key = round(inter * 2^14 / union). Exact rational order.
__global__ void k_keymat(const ull* __restrict__ bits,
                         const unsigned* __restrict__ deg, u16* __restrict__ keyM){
  __shared__ ull bi[64][33];
  __shared__ ull bj[64][33];
  __shared__ unsigned degi[64], degj[64];
  int ib = blockIdx.x, jb = blockIdx.y;
  int t = threadIdx.x;
  for (int idx = t; idx < 64*32; idx += 256){
    int r = idx >> 5, w = idx & 31;
    bi[r][w] = bits[(((size_t)(ib*64 + r)) << 5) + w];
    bj[r][w] = bits[(((size_t)(jb*64 + r)) << 5) + w];
  }
  if (t < 64){ degi[t] = deg[ib*64 + t]; degj[t] = deg[jb*64 + t]; }
  __syncthreads();
  for (int p = t; p < 4096; p += 256){
    int ii = p >> 6, jj = p & 63;
    int i = ib*64 + ii, j = jb*64 + jj;
    unsigned key = 0u;
    if (i != j){
      unsigned inter = 0;
      #pragma unroll
      for (int w = 0; w < 32; ++w) inter += (unsigned)__popcll(bi[ii][w] & bj[jj][w]);
      unsigned b = degi[ii] + degj[jj] - inter;
      if (b != 0u){
        unsigned num = (inter << KSH) + (b >> 1);
        key = num / b;
      }
    }
    keyM[((size_t)i << 11) + j] = (u16)key;
  }
}

// Fused Boruvka + finalization. One custom grid barrier + 3 LDS barriers per
// round (lock-free UF merge, redundant in every block -> identical lab state).
// Final phase: radix-select (no sort) + UF CC + shfl scans.
__global__ void __launch_bounds__(CT)
k_boruvka(const u16* __restrict__ keyM, ull* __restrict__ node_best /*[2][NN]*/,
          unsigned* __restrict__ bar,
          unsigned* __restrict__ labels_g, float* __restrict__ scale_g,
          unsigned* __restrict__ offs_g, unsigned* __restrict__ memb_g,
          float* __restrict__ P){
  __shared__ ull ed[NN];       // collected MSF edges; later plab overlay
  __shared__ ull cbest[NN];    // per-component best; later glist / sizes
  __shared__ alignas(16) unsigned lab[NN]; // comp label; later select hists / CC labels
  __shared__ unsigned nxtA[NN];            // UF parent; later off_l/cursor
  __shared__ unsigned partials[16];
  __shared__ unsigned selS[4];
  __shared__ unsigned gcntS;
  __shared__ unsigned cntS;
  int t = threadIdx.x;
  int b = blockIdx.x;
  if (t == 0) cntS = 0;
  for (int i = t; i < NN; i += CT) lab[i] = (unsigned)i;
  __syncthreads();

  for (int round = 0; round < 11; ++round){
    ull* nb = node_best + ((round & 1) ? NN : 0);
    // init merge state (visibility covered by gbar's internal barrier)
    for (int c = t; c < NN; c += CT){ cbest[c] = ~0ull; nxtA[c] = (unsigned)c; }
    // ---- best phase: one row per wave ----
    {
      int i = b*(CT/64) + (t >> 6);
      int lane = t & 63;
      unsigned ci = lab[i];
      const u16* row = keyM + ((size_t)i << 11);
      ull best = ~0ull;
      #pragma unroll
      for (int it = 0; it < 8; ++it){
        int j0 = it*256 + lane*4;
        ushort4 k4 = *(const ushort4*)(row + j0);
        uint4   c4 = *(const uint4*)(lab + j0);
        #pragma unroll
        for (int q = 0; q < 4; ++q){
          int j = j0 + q;
          unsigned key = (q==0)?k4.x:(q==1)?k4.y:(q==2)?k4.z:k4.w;
          unsigned cj  = (q==0)?c4.x:(q==1)?c4.y:(q==2)?c4.z:c4.w;
          if (j == i || cj == ci) continue;
          unsigned kp = KMAX16 - key;
          unsigned a  = (i < j) ? (unsigned)i : (unsigned)j;
          unsigned b2 = (i < j) ? (unsigned)j : (unsigned)i;
          ull v = (((ull)kp) << 22) | (((ull)a) << 11) | b2;
          if (v < best) best = v;
        }
      }
      for (int off = 32; off; off >>= 1){
        ull o = __shfl_xor(best, off);
        if (o < best) best = o;
      }
      if (lane == 0) nb[i] = best;
    }
    gbar(bar, (unsigned)(round + 1) * (unsigned)CB, t);
    // ---- merge: scatter, UF union + dedup collect, relabel (3 barriers) ----
    for (int i = t; i < NN; i += CT) atomicMin64(&cbest[lab[i]], nb[i]);
    __syncthreads();                                           // M1
    for (int c = t; c < NN; c += CT){
      ull v = cbest[c];
      if (v == ~0ull) continue;
      unsigned a = (unsigned)((v >> 11) & 2047u), b2 = (unsigned)(v & 2047u);
      unsigned la = lab[a], lb = lab[b2];
      if (la == lb) continue;
      unsigned other = (la == (unsigned)c) ? lb : la;
      if (!(cbest[other] == v && other < (unsigned)c)){
        unsigned idx = atomicAdd(&cntS, 1u);
        if (idx < (unsigned)NN) ed[idx] = v;
      }
      uf_union(nxtA, la, lb);
    }
    __syncthreads();                                           // M2
    for (int i = t; i < NN; i += CT) lab[i] = uf_find(nxtA, lab[i]);
    __syncthreads();                                           // M3
    if (cntS >= (unsigned)(NN-1)) break;   // identical in every block
  }
  if (b != 0) return;

  // ================= final phase (block 0 only) =================
  unsigned cnt = cntS; if (cnt > (unsigned)NN) cnt = NN;
  // ---- radix select: TGTM smallest of ed[0..cnt) by kp = val>>22 ----
  unsigned* h1 = lab;            // 129 buckets (kp>>7)
  unsigned* h2 = lab + 256;      // 128 buckets (kp&127)
  for (int k = t; k < 129+256; k += CT) if (k < 129 || k >= 256) lab[k] = 0u;
  if (t < 128) h2[t] = 0u;
  if (t == 0){ selS[0] = 128u; selS[1] = 1u; selS[2] = 127u; selS[3] = 1u; gcntS = 0u; }
  __syncthreads();
  for (int e = t; e < (int)cnt; e += CT) atomicAdd(&h1[(unsigned)(ed[e] >> 29)], 1u);
  __syncthreads();
  if (t == 0){
    unsigned c = 0;
    for (unsigned bk = 0; bk <= 128; ++bk){
      if (c + h1[bk] >= (unsigned)TGTM){ selS[0] = bk; selS[1] = (unsigned)TGTM - c; break; }
      c += h1[bk];
    }
  }
  __syncthreads();
  unsigned B1 = selS[0], r1 = selS[1];
  for (int e = t; e < (int)cnt; e += CT){
    ull v = ed[e];
    if ((unsigned)(v >> 29) == B1) atomicAdd(&h2[(unsigned)((v >> 22) & 127u)], 1u);
  }
  __syncthreads();
  if (t == 0){
    unsigned c = 0;
    for (unsigned bk = 0; bk < 128; ++bk){
      if (c + h2[bk] >= r1){ selS[2] = bk; selS[3] = r1 - c; break; }
      c += h2[bk];
    }
  }
  __syncthreads();
  unsigned B2 = selS[2], r2 = selS[3];
  unsigned kpSel = (B1 << 7) | B2;
  ull* glist = cbest;
  for (int e = t; e < (int)cnt; e += CT){
    ull v = ed[e];
    if ((unsigned)(v >> 22) == kpSel){
      unsigned idx = atomicAdd(&gcntS, 1u);
      glist[idx] = v;
    }
  }
  // init UF parents over nodes
  for (int c = t; c < NN; c += CT) nxtA[c] = (unsigned)c;
  __syncthreads();
  unsigned gc = gcntS;
  // ---- UF over selected edges ----
  for (int e = t; e < (int)cnt; e += CT){
    ull v = ed[e];
    unsigned kp = (unsigned)(v >> 22);
    bool sel;
    if (kp < kpSel) sel = true;
    else if (kp > kpSel) sel = false;
    else {
      unsigned r = 0;
      for (unsigned j = 0; j < gc; ++j) r += (glist[j] < v) ? 1u : 0u;
      sel = (r < r2);
    }
    if (sel){
      unsigned a = (unsigned)((v >> 11) & 2047u), b2 = (unsigned)(v & 2047u);
      uf_union(nxtA, a, b2);
    }
  }
  __syncthreads();
  // lab[i] = component root = MIN MEMBER id (hook-to-min invariant)
  for (int i = t; i < NN; i += CT) lab[i] = uf_find(nxtA, (unsigned)i);
  __syncthreads();
  // ---- labels = rank of class by min member (shfl scans) ----
  unsigned* plab  = (unsigned*)ed;
  unsigned* sizes = (unsigned*)cbest;
  int i0 = 2*t, i1 = 2*t + 1;
  unsigned f0 = (lab[i0] == (unsigned)i0) ? 1u : 0u;
  unsigned f1 = (lab[i1] == (unsigned)i1) ? 1u : 0u;
  unsigned s = f0 + f1;
  unsigned incl = block_scan_incl(s, partials, t);
  plab[i0] = incl - s; plab[i1] = incl - s + f0;
  for (int c = t; c < MS; c += CT) sizes[c] = 0u;
  __syncthreads();
  for (int i = t; i < NN; i += CT){
    unsigned L = plab[lab[i]];
    labels_g[i] = L;
    if (L < (unsigned)MS) atomicAdd(&sizes[L], 1u);
  }
  __syncthreads();
  for (int c = t; c < MS; c += CT) scale_g[c] = 1.0f / sqrtf((float)sizes[c] + 1e-10f);
  // offs: exclusive scan of sizes
  unsigned* off_l  = nxtA;         // UF parents dead now
  unsigned* cursor = nxtA + 1024;
  unsigned my = (t < MS) ? sizes[t] : 0u;
  unsigned incl2 = block_scan_incl(my, partials, t);
  if (t < MS){
    unsigned ex = incl2 - my;
    off_l[t] = ex; offs_g[t] = ex;
  }
  if (t == 0) offs_g[MS] = (unsigned)NN;
  __syncthreads();
  for (int c = t; c < MS; c += CT) cursor[c] = off_l[c];
  __syncthreads();
  for (int i = t; i < NN; i += CT){
    unsigned L = plab[lab[i]];
    unsigned pos = atomicAdd(&cursor[L], 1u);
    memb_g[pos] = (unsigned)i;
  }
  for (int i = t; i < NN; i += CT){
    unsigned L = plab[lab[i]];
    P[((size_t)i << 9) + L] = 1.0f / sqrtf((float)sizes[L] + 1e-10f);
  }
}

// X_coarse: grid (cluster, d-tile of 128), 128 threads; LDS member list, 8-deep ILP.
__global__ void k_coarseX(const float* __restrict__ X, const unsigned* __restrict__ offs,
                          const unsigned* __restrict__ memb, const float* __restrict__ scale,
                          float* __restrict__ Xc){
  __shared__ unsigned mlist[NN];
  int c = blockIdx.x;
  int d = blockIdx.y*128 + threadIdx.x;
  unsigned o = offs[c], e = offs[c+1];
  int nm = (int)(e - o);
  for (int k = threadIdx.x; k < nm; k += 128) mlist[k] = memb[o + k];
  __syncthreads();
  float a0=0.f,a1=0.f,a2=0.f,a3=0.f,a4=0.f,a5=0.f,a6=0.f,a7=0.f;
  int k = 0;
  for (; k + 8 <= nm; k += 8){
    a0 += X[((size_t)mlist[k+0] << 9) + d];
    a1 += X[((size_t)mlist[k+1] << 9) + d];
    a2 += X[((size_t)mlist[k+2] << 9) + d];
    a3 += X[((size_t)mlist[k+3] << 9) + d];
    a4 += X[((size_t)mlist[k+4] << 9) + d];
    a5 += X[((size_t)mlist[k+5] << 9) + d];
    a6 += X[((size_t)mlist[k+6] << 9) + d];
    a7 += X[((size_t)mlist[k+7] << 9) + d];
  }
  for (; k < nm; ++k) a0 += X[((size_t)mlist[k] << 9) + d];
  float acc = ((a0+a1)+(a2+a3)) + ((a4+a5)+(a6+a7));
  Xc[((size_t)c << 9) + d] = acc * scale[c];
}

// A_coarse: grid (cluster, slice of <=64 members), LDS histogram per slice.
__global__ void k_coarseA(const ull* __restrict__ bits,
                          const unsigned* __restrict__ labels,
                          const unsigned* __restrict__ offs, const unsigned* __restrict__ memb,
                          const float* __restrict__ scale, float* __restrict__ Ac){
  __shared__ float row[MS];
  __shared__ unsigned labS[NN];
  __shared__ unsigned mlist[ASL];
  int c = blockIdx.x, sl = blockIdx.y, t = threadIdx.x;
  unsigned o0 = offs[c], e = offs[c+1];
  unsigned o = o0 + (unsigned)sl*ASL;
  if (o >= e) return;                       // uniform per block
  int nm = (int)min((unsigned)ASL, e - o);
  for (int j = t; j < MS; j += 256) row[j] = 0.0f;
  for (int i = t; i < NN; i += 256) labS[i] = labels[i];
  if (t < nm) mlist[t] = memb[o + t];
  __syncthreads();
  for (int idx = t; idx < nm*WW; idx += 256){
    unsigned m = mlist[idx >> 5];
    int w = idx & 31;
    ull word = bits[((size_t)m << 5) + w];
    while (word){
      int bb = __ffsll((long long)word) - 1;
      unsigned j = (unsigned)(w*64 + bb);
      atomicAdd(&row[labS[j]], 1.0f);       // LDS atomic
      word &= word - 1ull;
    }
  }
  __syncthreads();
  float sc = scale[c];
  bool single = (e - o0) <= (unsigned)ASL;
  if (single){
    for (int j = t; j < MS; j += 256)
      Ac[((size_t)c << 9) + j] = row[j] * sc * scale[j];
  } else {
    for (int j = t; j < MS; j += 256){
      float v = row[j];
      if (v != 0.0f) atomicAdd(&Ac[((size_t)c << 9) + j], v * sc * scale[j]);
    }
  }
}

extern "C" void kernel_launch(void* const* d_in, const int* in_sizes, int n_in,
                              void* d_out, int out_size, void* d_ws, size_t ws_size,
                              hipStream_t stream) {
  const float* X = (const float*)d_in[0];
  const float* A = (const float*)d_in[1];
  float* out = (float*)d_out;
  char* ws = (char*)d_ws;
  ull*      bits     = (ull*)     (ws + 0x000000);  // 512 KB, live whole run
  unsigned* deg      = (unsigned*)(ws + 0x080000);  // 8 KB (dead after keymat)
  ull*      nodebest = (ull*)     (ws + 0x084000);  // 32 KB double-buffered
  unsigned* labels   = (unsigned*)(ws + 0x08D000);  // 8 KB
  float*    scale    = (float*)   (ws + 0x08F000);  // 2 KB
  unsigned* bar      = (unsigned*)(ws + 0x08F800);  // 8 B grid-barrier counter
  unsigned* memb     = (unsigned*)(ws + 0x084000);  // overlays nodebest (8 KB)
  unsigned* offs     = (unsigned*)(ws + 0x080000);  // overlays deg (2052 B)
  u16*      keyM     = (u16*)     (ws + 0x090000);  // 8 MB

  float* Xc = out;
  float* Ac = out + MS*MS;
  float* P  = out + 2*MS*MS;

  hipMemsetAsync(bar, 0, 8, stream);
  hipMemsetAsync(P,  0, (size_t)NN*MS*sizeof(float), stream);   // P region (4 MB)
  hipMemsetAsync(Ac, 0, (size_t)MS*MS*sizeof(float), stream);   // Ac region (1 MB)

  k_build_bits<<<(NN*WW)/256, 256, 0, stream>>>(A, bits, deg);
  k_keymat<<<dim3(NN/64, NN/64), 256, 0, stream>>>(bits, deg, keyM);

  void* args[] = { (void*)&keyM, (void*)&nodebest, (void*)&bar,
                   (void*)&labels, (void*)&scale, (void*)&offs, (void*)&memb, (void*)&P };
  hipLaunchCooperativeKernel((void*)k_boruvka, dim3(CB), dim3(CT), args, 0, stream);

  k_coarseX<<<dim3(MS, DD/128), 128, 0, stream>>>(X, offs, memb, scale, Xc);
  k_coarseA<<<dim3(MS, NSL), 256, 0, stream>>>(bits, labels, offs, memb, scale, Ac);
}

// Round 11
// 272.018 us; speedup vs baseline: 1.5405x; 1.2438x over previous
//
#include <hip/hip_runtime.h>

#define NN 2048
#define WW 32            // u64 words per bitmask row
#define DD 512
#define MS 512           // super nodes
#define TGTM 1536        // merges = NN - MS
#define KSH 14           // key scale bits: 2^14 > union_max^2 -> exact rational order
#define KMAX16 16384u
#define CB 128           // cooperative blocks (1 row per wave: 128*16 = 2048)
#define CT 1024
#define ASL 64           // coarseA members per slice
#define NSL 25
#define MSL 128          // coarseX members per slice
#define NSX 16           // 16*128 = 2048 covers any cluster

typedef unsigned long long ull;
typedef unsigned short u16;

__device__ __forceinline__ void atomicMin64(ull* p, ull v){
  ull old = *p;
  while (v < old){
    ull assumed = old;
    old = atomicCAS(p, assumed, v);
    if (old == assumed) break;
  }
}

// Lock-free union-find on LDS: hook larger root under smaller (root = min id),
// path halving on find (benign race: writes are always valid ancestors).
__device__ __forceinline__ unsigned uf_find(unsigned* par, unsigned x){
  while (true){
    unsigned p = par[x];
    if (p == x) return x;
    unsigned g = par[p];
    if (g == p) return p;
    par[x] = g;
    x = g;
  }
}
__device__ __forceinline__ void uf_union(unsigned* par, unsigned x, unsigned y){
  while (true){
    unsigned rx = uf_find(par, x), ry = uf_find(par, y);
    if (rx == ry) return;
    if (rx > ry){ unsigned tm = rx; rx = ry; ry = tm; }
    if (atomicCAS(&par[ry], ry, rx) == ry) return;
    x = rx; y = ry;
  }
}

// Inclusive block scan over CT=1024 threads: shfl wave scan + 16 partials.
__device__ __forceinline__ unsigned block_scan_incl(unsigned v, unsigned* partials, int t){
  int lane = t & 63, wv = t >> 6;
  unsigned x = v;
  #pragma unroll
  for (int off = 1; off < 64; off <<= 1){
    unsigned n = __shfl_up(x, off, 64);
    if (lane >= off) x += n;
  }
  __syncthreads();
  if (lane == 63) partials[wv] = x;
  __syncthreads();
  if (wv == 0){
    unsigned p = (lane < 16) ? partials[lane] : 0u;
    #pragma unroll
    for (int off = 1; off < 16; off <<= 1){
      unsigned n = __shfl_up(p, off, 64);
      if (lane >= off) p += n;
    }
    if (lane < 16) partials[lane] = p;
  }
  __syncthreads();
  if (wv > 0) x += partials[wv-1];
  return x;
}

// Hand-rolled grid barrier: single monotone counter, no reset (target = k*CB).
__device__ __forceinline__ void gbar(unsigned* cnt, unsigned target, int t){
  __syncthreads();
  if (t == 0){
    __threadfence();
    __hip_atomic_fetch_add(cnt, 1u, __ATOMIC_RELEASE, __HIP_MEMORY_SCOPE_AGENT);
    while (__hip_atomic_load(cnt, __ATOMIC_RELAXED, __HIP_MEMORY_SCOPE_AGENT) < target)
      __builtin_amdgcn_s_sleep(1);
    __threadfence();
  }
  __syncthreads();
}

// Build 2048-bit adjacency bitmasks + degrees (wave-reduced).
__global__ void k_build_bits(const float* __restrict__ A, ull* __restrict__ bits,
                             unsigned* __restrict__ deg){
  int gid = blockIdx.x*blockDim.x + threadIdx.x;   // NN*WW threads
  int i = gid >> 5, w = gid & 31;
  const float4* row = (const float4*)(A + ((size_t)i << 11) + (w << 6));
  ull m = 0ull;
  #pragma unroll
  for (int k = 0; k < 16; ++k){
    float4 v = row[k];
    if (v.x > 0.0f) m |= (1ull << (4*k+0));
    if (v.y > 0.0f) m |= (1ull << (4*k+1));
    if (v.z > 0.0f) m |= (1ull << (4*k+2));
    if (v.w > 0.0f) m |= (1ull << (4*k+3));
  }
  bits[((size_t)i << 5) + w] = m;
  unsigned p = (unsigned)__popcll(m);
  for (int off = 16; off; off >>= 1) p += __shfl_xor(p, off, 32);
  if (w == 0) deg[i] = p;
}

// Key matrix (u16), 4x4 register-tiled: each thread owns rows tr..tr+3 x cols
// tc..tc+3; per w loads 4+4 ds_read_b64 for 16 popc-ANDs (4x fewer LDS reads).
__global__ void k_keymat(const ull* __restrict__ bits,
                         const unsigned* __restrict__ deg, u16* __restrict__ keyM){
  __shared__ ull bi[64][33];
  __shared__ ull bj[64][33];
  __shared__ unsigned degi[64], degj[64];
  int ib = blockIdx.x, jb = blockIdx.y;
  int t = threadIdx.x;
  for (int idx = t; idx < 64*32; idx += 256){
    int r = idx >> 5, w = idx & 31;
    bi[r][w] = bits[(((size_t)(ib*64 + r)) << 5) + w];
    bj[r][w] = bits[(((size_t)(jb*64 + r)) << 5) + w];
  }
  if (t < 64){ degi[t] = deg[ib*64 + t]; degj[t] = deg[jb*64 + t]; }
  __syncthreads();
  int tr = (t >> 4) << 2;      // row tile base (0..60)
  int tc = (t & 15) << 2;      // col tile base (0..60)
  unsigned inter[4][4];
  #pragma unroll
  for (int r = 0; r < 4; ++r)
    #pragma unroll
    for (int c = 0; c < 4; ++c) inter[r][c] = 0u;
  #pragma unroll 8
  for (int w = 0; w < 32; ++w){
    ull a0 = bi[tr+0][w], a1 = bi[tr+1][w], a2 = bi[tr+2][w], a3 = bi[tr+3][w];
    ull b0 = bj[tc+0][w], b1 = bj[tc+1][w], b2 = bj[tc+2][w], b3 = bj[tc+3][w];
    inter[0][0] += (unsigned)__popcll(a0 & b0);
    inter[0][1] += (unsigned)__popcll(a0 & b1);
    inter[0][2] += (unsigned)__popcll(a0 & b2);
    inter[0][3] += (unsigned)__popcll(a0 & b3);
    inter[1][0] += (unsigned)__popcll(a1 & b0);
    inter[1][1] += (unsigned)__popcll(a1 & b1);
    inter[1][2] += (unsigned)__popcll(a1 & b2);
    inter[1][3] += (unsigned)__popcll(a1 & b3);
    inter[2][0] += (unsigned)__popcll(a2 & b0);
    inter[2][1] += (unsigned)__popcll(a2 & b1);
    inter[2][2] += (unsigned)__popcll(a2 & b2);
    inter[2][3] += (unsigned)__popcll(a2 & b3);
    inter[3][0] += (unsigned)__popcll(a3 & b0);
    inter[3][1] += (unsigned)__popcll(a3 & b1);
    inter[3][2] += (unsigned)__popcll(a3 & b2);
    inter[3][3] += (unsigned)__popcll(a3 & b3);
  }
  #pragma unroll
  for (int r = 0; r < 4; ++r){
    int i = ib*64 + tr + r;
    u16 kv[4];
    #pragma unroll
    for (int c = 0; c < 4; ++c){
      int j = jb*64 + tc + c;
      unsigned key = 0u;
      if (i != j){
        unsigned iv = inter[r][c];
        unsigned b = degi[tr+r] + degj[tc+c] - iv;
        if (b != 0u){
          unsigned num = (iv << KSH) + (b >> 1);
          key = num / b;
        }
      }
      kv[c] = (u16)key;
    }
    *(ushort4*)(keyM + (((size_t)i) << 11) + (jb*64 + tc)) =
        make_ushort4(kv[0], kv[1], kv[2], kv[3]);
  }
}

// Fused Boruvka + finalization. One custom grid barrier + 3 LDS barriers per
// round (lock-free UF merge, redundant in every block -> identical lab state).
// Final phase: radix-select (no sort) + UF CC + shfl scans.
__global__ void __launch_bounds__(CT)
k_boruvka(const u16* __restrict__ keyM, ull* __restrict__ node_best /*[2][NN]*/,
          unsigned* __restrict__ bar,
          unsigned* __restrict__ labels_g, float* __restrict__ scale_g,
          unsigned* __restrict__ offs_g, unsigned* __restrict__ memb_g,
          float* __restrict__ P){
  __shared__ ull ed[NN];       // collected MSF edges; later plab overlay
  __shared__ ull cbest[NN];    // per-component best; later glist / sizes
  __shared__ alignas(16) unsigned lab[NN]; // comp label; later select hists / CC labels
  __shared__ unsigned nxtA[NN];            // UF parent; later off_l/cursor
  __shared__ unsigned partials[16];
  __shared__ unsigned selS[4];
  __shared__ unsigned gcntS;
  __shared__ unsigned cntS;
  int t = threadIdx.x;
  int b = blockIdx.x;
  if (t == 0) cntS = 0;
  for (int i = t; i < NN; i += CT) lab[i] = (unsigned)i;
  __syncthreads();

  for (int round = 0; round < 11; ++round){
    ull* nb = node_best + ((round & 1) ? NN : 0);
    for (int c = t; c < NN; c += CT){ cbest[c] = ~0ull; nxtA[c] = (unsigned)c; }
    // ---- best phase: one row per wave ----
    {
      int i = b*(CT/64) + (t >> 6);
      int lane = t & 63;
      unsigned ci = lab[i];
      const u16* row = keyM + ((size_t)i << 11);
      ull best = ~0ull;
      #pragma unroll
      for (int it = 0; it < 8; ++it){
        int j0 = it*256 + lane*4;
        ushort4 k4 = *(const ushort4*)(row + j0);
        uint4   c4 = *(const uint4*)(lab + j0);
        #pragma unroll
        for (int q = 0; q < 4; ++q){
          int j = j0 + q;
          unsigned key = (q==0)?k4.x:(q==1)?k4.y:(q==2)?k4.z:k4.w;
          unsigned cj  = (q==0)?c4.x:(q==1)?c4.y:(q==2)?c4.z:c4.w;
          if (j == i || cj == ci) continue;
          unsigned kp = KMAX16 - key;
          unsigned a  = (i < j) ? (unsigned)i : (unsigned)j;
          unsigned b2 = (i < j) ? (unsigned)j : (unsigned)i;
          ull v = (((ull)kp) << 22) | (((ull)a) << 11) | b2;
          if (v < best) best = v;
        }
      }
      for (int off = 32; off; off >>= 1){
        ull o = __shfl_xor(best, off);
        if (o < best) best = o;
      }
      if (lane == 0) nb[i] = best;
    }
    gbar(bar, (unsigned)(round + 1) * (unsigned)CB, t);
    // ---- merge: scatter, UF union + dedup collect, relabel (3 barriers) ----
    for (int i = t; i < NN; i += CT) atomicMin64(&cbest[lab[i]], nb[i]);
    __syncthreads();                                           // M1
    for (int c = t; c < NN; c += CT){
      ull v = cbest[c];
      if (v == ~0ull) continue;
      unsigned a = (unsigned)((v >> 11) & 2047u), b2 = (unsigned)(v & 2047u);
      unsigned la = lab[a], lb = lab[b2];
      if (la == lb) continue;
      unsigned other = (la == (unsigned)c) ? lb : la;
      if (!(cbest[other] == v && other < (unsigned)c)){
        unsigned idx = atomicAdd(&cntS, 1u);
        if (idx < (unsigned)NN) ed[idx] = v;
      }
      uf_union(nxtA, la, lb);
    }
    __syncthreads();                                           // M2
    for (int i = t; i < NN; i += CT) lab[i] = uf_find(nxtA, lab[i]);
    __syncthreads();                                           // M3
    if (cntS >= (unsigned)(NN-1)) break;   // identical in every block
  }
  if (b != 0) return;

  // ================= final phase (block 0 only) =================
  unsigned cnt = cntS; if (cnt > (unsigned)NN) cnt = NN;
  // ---- radix select: TGTM smallest of ed[0..cnt) by kp = val>>22 ----
  unsigned* h1 = lab;            // 129 buckets (kp>>7)
  unsigned* h2 = lab + 256;      // 128 buckets (kp&127)
  for (int k = t; k < 129+256; k += CT) if (k < 129 || k >= 256) lab[k] = 0u;
  if (t < 128) h2[t] = 0u;
  if (t == 0){ selS[0] = 128u; selS[1] = 1u; selS[2] = 127u; selS[3] = 1u; gcntS = 0u; }
  __syncthreads();
  for (int e = t; e < (int)cnt; e += CT) atomicAdd(&h1[(unsigned)(ed[e] >> 29)], 1u);
  __syncthreads();
  if (t == 0){
    unsigned c = 0;
    for (unsigned bk = 0; bk <= 128; ++bk){
      if (c + h1[bk] >= (unsigned)TGTM){ selS[0] = bk; selS[1] = (unsigned)TGTM - c; break; }
      c += h1[bk];
    }
  }
  __syncthreads();
  unsigned B1 = selS[0], r1 = selS[1];
  for (int e = t; e < (int)cnt; e += CT){
    ull v = ed[e];
    if ((unsigned)(v >> 29) == B1) atomicAdd(&h2[(unsigned)((v >> 22) & 127u)], 1u);
  }
  __syncthreads();
  if (t == 0){
    unsigned c = 0;
    for (unsigned bk = 0; bk < 128; ++bk){
      if (c + h2[bk] >= r1){ selS[2] = bk; selS[3] = r1 - c; break; }
      c += h2[bk];
    }
  }
  __syncthreads();
  unsigned B2 = selS[2], r2 = selS[3];
  unsigned kpSel = (B1 << 7) | B2;
  ull* glist = cbest;
  for (int e = t; e < (int)cnt; e += CT){
    ull v = ed[e];
    if ((unsigned)(v >> 22) == kpSel){
      unsigned idx = atomicAdd(&gcntS, 1u);
      glist[idx] = v;
    }
  }
  for (int c = t; c < NN; c += CT) nxtA[c] = (unsigned)c;
  __syncthreads();
  unsigned gc = gcntS;
  // ---- UF over selected edges ----
  for (int e = t; e < (int)cnt; e += CT){
    ull v = ed[e];
    unsigned kp = (unsigned)(v >> 22);
    bool sel;
    if (kp < kpSel) sel = true;
    else if (kp > kpSel) sel = false;
    else {
      unsigned r = 0;
      for (unsigned j = 0; j < gc; ++j) r += (glist[j] < v) ? 1u : 0u;
      sel = (r < r2);
    }
    if (sel){
      unsigned a = (unsigned)((v >> 11) & 2047u), b2 = (unsigned)(v & 2047u);
      uf_union(nxtA, a, b2);
    }
  }
  __syncthreads();
  // lab[i] = component root = MIN MEMBER id (hook-to-min invariant)
  for (int i = t; i < NN; i += CT) lab[i] = uf_find(nxtA, (unsigned)i);
  __syncthreads();
  // ---- labels = rank of class by min member (shfl scans) ----
  unsigned* plab  = (unsigned*)ed;
  unsigned* sizes = (unsigned*)cbest;
  int i0 = 2*t, i1 = 2*t + 1;
  unsigned f0 = (lab[i0] == (unsigned)i0) ? 1u : 0u;
  unsigned f1 = (lab[i1] == (unsigned)i1) ? 1u : 0u;
  unsigned s = f0 + f1;
  unsigned incl = block_scan_incl(s, partials, t);
  plab[i0] = incl - s; plab[i1] = incl - s + f0;
  for (int c = t; c < MS; c += CT) sizes[c] = 0u;
  __syncthreads();
  for (int i = t; i < NN; i += CT){
    unsigned L = plab[lab[i]];
    labels_g[i] = L;
    if (L < (unsigned)MS) atomicAdd(&sizes[L], 1u);
  }
  __syncthreads();
  for (int c = t; c < MS; c += CT) scale_g[c] = 1.0f / sqrtf((float)sizes[c] + 1e-10f);
  unsigned* off_l  = nxtA;
  unsigned* cursor = nxtA + 1024;
  unsigned my = (t < MS) ? sizes[t] : 0u;
  unsigned incl2 = block_scan_incl(my, partials, t);
  if (t < MS){
    unsigned ex = incl2 - my;
    off_l[t] = ex; offs_g[t] = ex;
  }
  if (t == 0) offs_g[MS] = (unsigned)NN;
  __syncthreads();
  for (int c = t; c < MS; c += CT) cursor[c] = off_l[c];
  __syncthreads();
  for (int i = t; i < NN; i += CT){
    unsigned L = plab[lab[i]];
    unsigned pos = atomicAdd(&cursor[L], 1u);
    memb_g[pos] = (unsigned)i;
  }
  for (int i = t; i < NN; i += CT){
    unsigned L = plab[lab[i]];
    P[((size_t)i << 9) + L] = 1.0f / sqrtf((float)sizes[L] + 1e-10f);
  }
}

// X_coarse: grid (cluster, d-tile of 128, member-slice of 128); LDS member
// list + 8-deep ILP. Single-slice clusters store; multi-slice atomicAdd onto
// pre-zeroed Xc. Worst block: 16 ILP-8 batches (~3us) -- no straggler.
__global__ void k_coarseX(const float* __restrict__ X, const unsigned* __restrict__ offs,
                          const unsigned* __restrict__ memb, const float* __restrict__ scale,
                          float* __restrict__ Xc){
  __shared__ unsigned mlist[MSL];
  int c = blockIdx.x;
  int d = blockIdx.y*128 + threadIdx.x;
  int sl = blockIdx.z;
  unsigned o0 = offs[c], e = offs[c+1];
  unsigned o = o0 + (unsigned)sl*MSL;
  if (o >= e) return;                       // uniform per block
  int nm = (int)min((unsigned)MSL, e - o);
  if (threadIdx.x < nm) mlist[threadIdx.x] = memb[o + threadIdx.x];
  __syncthreads();
  float a0=0.f,a1=0.f,a2=0.f,a3=0.f,a4=0.f,a5=0.f,a6=0.f,a7=0.f;
  int k = 0;
  for (; k + 8 <= nm; k += 8){
    a0 += X[((size_t)mlist[k+0] << 9) + d];
    a1 += X[((size_t)mlist[k+1] << 9) + d];
    a2 += X[((size_t)mlist[k+2] << 9) + d];
    a3 += X[((size_t)mlist[k+3] << 9) + d];
    a4 += X[((size_t)mlist[k+4] << 9) + d];
    a5 += X[((size_t)mlist[k+5] << 9) + d];
    a6 += X[((size_t)mlist[k+6] << 9) + d];
    a7 += X[((size_t)mlist[k+7] << 9) + d];
  }
  for (; k < nm; ++k) a0 += X[((size_t)mlist[k] << 9) + d];
  float acc = (((a0+a1)+(a2+a3)) + ((a4+a5)+(a6+a7))) * scale[c];
  if (e - o0 <= (unsigned)MSL) Xc[((size_t)c << 9) + d] = acc;
  else atomicAdd(&Xc[((size_t)c << 9) + d], acc);
}

// A_coarse: grid (cluster, slice of <=64 members), LDS histogram per slice.
__global__ void k_coarseA(const ull* __restrict__ bits,
                          const unsigned* __restrict__ labels,
                          const unsigned* __restrict__ offs, const unsigned* __restrict__ memb,
                          const float* __restrict__ scale, float* __restrict__ Ac){
  __shared__ float row[MS];
  __shared__ unsigned labS[NN];
  __shared__ unsigned mlist[ASL];
  int c = blockIdx.x, sl = blockIdx.y, t = threadIdx.x;
  unsigned o0 = offs[c], e = offs[c+1];
  unsigned o = o0 + (unsigned)sl*ASL;
  if (o >= e) return;                       // uniform per block
  int nm = (int)min((unsigned)ASL, e - o);
  for (int j = t; j < MS; j += 256) row[j] = 0.0f;
  for (int i = t; i < NN; i += 256) labS[i] = labels[i];
  if (t < nm) mlist[t] = memb[o + t];
  __syncthreads();
  for (int idx = t; idx < nm*WW; idx += 256){
    unsigned m = mlist[idx >> 5];
    int w = idx & 31;
    ull word = bits[((size_t)m << 5) + w];
    while (word){
      int bb = __ffsll((long long)word) - 1;
      unsigned j = (unsigned)(w*64 + bb);
      atomicAdd(&row[labS[j]], 1.0f);       // LDS atomic
      word &= word - 1ull;
    }
  }
  __syncthreads();
  float sc = scale[c];
  bool single = (e - o0) <= (unsigned)ASL;
  if (single){
    for (int j = t; j < MS; j += 256)
      Ac[((size_t)c << 9) + j] = row[j] * sc * scale[j];
  } else {
    for (int j = t; j < MS; j += 256){
      float v = row[j];
      if (v != 0.0f) atomicAdd(&Ac[((size_t)c << 9) + j], v * sc * scale[j]);
    }
  }
}

extern "C" void kernel_launch(void* const* d_in, const int* in_sizes, int n_in,
                              void* d_out, int out_size, void* d_ws, size_t ws_size,
                              hipStream_t stream) {
  const float* X = (const float*)d_in[0];
  const float* A = (const float*)d_in[1];
  float* out = (float*)d_out;
  char* ws = (char*)d_ws;
  ull*      bits     = (ull*)     (ws + 0x000000);  // 512 KB, live whole run
  unsigned* deg      = (unsigned*)(ws + 0x080000);  // 8 KB (dead after keymat)
  ull*      nodebest = (ull*)     (ws + 0x084000);  // 32 KB double-buffered
  unsigned* labels   = (unsigned*)(ws + 0x08D000);  // 8 KB
  float*    scale    = (float*)   (ws + 0x08F000);  // 2 KB
  unsigned* bar      = (unsigned*)(ws + 0x08F800);  // 8 B grid-barrier counter
  unsigned* memb     = (unsigned*)(ws + 0x084000);  // overlays nodebest (8 KB)
  unsigned* offs     = (unsigned*)(ws + 0x080000);  // overlays deg (2052 B)
  u16*      keyM     = (u16*)     (ws + 0x090000);  // 8 MB

  float* Xc = out;
  float* Ac = out + MS*MS;
  float* P  = out + 2*MS*MS;

  hipMemsetAsync(bar, 0, 8, stream);
  hipMemsetAsync(out, 0, (size_t)out_size*sizeof(float), stream);  // Xc+Ac+P (6 MB)

  k_build_bits<<<(NN*WW)/256, 256, 0, stream>>>(A, bits, deg);
  k_keymat<<<dim3(NN/64, NN/64), 256, 0, stream>>>(bits, deg, keyM);

  void* args[] = { (void*)&keyM, (void*)&nodebest, (void*)&bar,
                   (void*)&labels, (void*)&scale, (void*)&offs, (void*)&memb, (void*)&P };
  hipLaunchCooperativeKernel((void*)k_boruvka, dim3(CB), dim3(CT), args, 0, stream);

  k_coarseX<<<dim3(MS, DD/128, NSX), 128, 0, stream>>>(X, offs, memb, scale, Xc);
  k_coarseA<<<dim3(MS, NSL), 256, 0, stream>>>(bits, labels, offs, memb, scale, Ac);
}